// Round 5
// baseline (890.455 us; speedup 1.0000x reference)
//
#include <hip/hip_runtime.h>
#include <hip/hip_fp16.h>
#include <cstdint>
#include <cstddef>

// x[512,4096] fp32 ; gate/up codes [11008,4096] i32 ; down codes [4096,11008] i32
// absmax blocks of 64 along K ; out [512,4096] fp32
//
// R9 (2nd resubmit — two GPUAcquisitionTimeouts, kernel has never run):
// barrier-free K-loop (convoy theory):
//  - R6/R7/R8 all pinned at ~230us despite 4x changes in LDS/VALU/occupancy:
//    per-kt __syncthreads around the shared LDS B-tile convoys 4 waves on
//    every unhidden memory latency. 64 barriers x ~convoy = the whole time.
//  - Each wave now dequants its OWN B fragments in registers: per-lane code
//    loads straight from global (2x int4 per (j,kk)), pair-lookup in a
//    read-only 256-word ptab (init + one __syncthreads, then NO sync in
//    the loop). No Bb tile, no lgkm barrier, waves fully independent.
//  - Codes prefetched 1 kt ahead in regs (cq[8], af[2]); issue order per kt:
//    DEQ(cur) -> A kk0 (L2) -> next codes (HBM, newest) -> MFMA kk0 (waits
//    A kk0, keeps codes in flight) -> A kk1 -> MFMA kk1. In-order vmcnt
//    never force-drains the HBM code queue mid-iteration.
//  - Cost accepted: 4x code reads (L2-absorbed), 3x DEQ VALU (VALU was 8%),
//    scattered ptab reads (~2-4 way, near-free). LDS 11KB -> 1KB.

using float4v = __attribute__((ext_vector_type(4))) float;
using half8   = __attribute__((ext_vector_type(8))) _Float16;

__constant__ float NF4TAB[16] = {
  -1.0f, -0.6961928009986877f, -0.5250730514526367f, -0.39491748809814453f,
  -0.28444138169288635f, -0.18477343022823334f, -0.09105003625154495f, 0.0f,
  0.07958029955625534f, 0.16093020141124725f, 0.24611230194568634f,
  0.33791524171829224f, 0.44070982933044434f, 0.5626170039176941f,
  0.7229568362236023f, 1.0f };

// Packed A layout (M=512 fixed): element (m,k) at
//   (((k>>5)*32 + (m>>4))*64 + ((k>>3)&3)*16 + (m&15))*8 + (k&7)
// -> frag (mb,kb): 64 lanes x 16B dense at (kb*32+mb)*512 + lane*8.

// C[512 x N] = A_packed * dequant(codes[N x K])^T
// Block 512M x 32N, BK=64, 4 waves, wave tile 128x32 (8x2 MFMA 16x16x32 f16).
// B-operand layout (16x16x32): lane holds B[k=(lane>>4)*8+e][n=lane&15].
// ATOMIC=false: r2 selects gate/up matrix; C stored f16 PACKED.
// ATOMIC=true : r2 = K-chunk (split-K); fp32 atomicAdd into row-major outF.
template <bool ATOMIC>
__global__ __launch_bounds__(256, 3) void gemm_nf4(
    const __half* __restrict__ Apk,
    const int* __restrict__ c0, const float* __restrict__ am0,
    const int* __restrict__ c1, const float* __restrict__ am1,
    __half* __restrict__ o0, __half* __restrict__ o1,
    float* __restrict__ outF,
    int N, int K, int Kc, int Ntiles)
{
  __shared__ unsigned ptab[256];         // packed f16 pair {tab[lo],tab[hi]}

  const int tid  = threadIdx.x;
  const int lane = tid & 63;
  const int wave = tid >> 6;
  const int l15  = lane & 15;
  const int hi8  = (lane >> 4) << 3;

  {
    __half2 pr = __floats2half2_rn(NF4TAB[tid & 15], NF4TAB[tid >> 4]);
    ptab[tid] = *(const unsigned*)&pr;
  }
  __syncthreads();                       // ptab visible; ONLY barrier.

  int nt, r2;
  if (ATOMIC) {
    // Pin each K-chunk to an XCD pair so its A-slice stays in that L2.
    const int xcd  = blockIdx.x & 7;
    const int slot = blockIdx.x >> 3;            // 0..63
    r2 = xcd >> 1;                               // K-chunk 0..3
    nt = (xcd & 1) * (Ntiles >> 1) + slot;       // 0..127
  } else {
    const int nwg = gridDim.x;
    const int bid = (blockIdx.x & 7) * (nwg >> 3) + (blockIdx.x >> 3);
    nt = bid % Ntiles;
    r2 = bid / Ntiles;                           // matrix select
  }

  const int k0 = ATOMIC ? r2 * Kc : 0;
  const int nk = Kc >> 6;
  const int* codes  = (!ATOMIC && r2) ? c1 : c0;
  const float* amax = (!ATOMIC && r2) ? am1 : am0;
  __half* outH      = (!ATOMIC && r2) ? o1 : o0;

  const int col0 = nt * 32;
  const int Kb   = K >> 6;

  // per-lane code/absmax streams. j=0 row: col0+l15 ; j=1 row: +16.
  // element k = kt*64 + kk*32 + hi8 + e  ->  int4 index kt*16 + kk*8 + {0,1}
  const int rowA = col0 + l15;
  const int4*  c4a = (const int4*)(codes + (size_t)rowA * K + k0 + hi8);
  const int4*  c4b = (const int4*)(codes + (size_t)(rowA + 16) * K + k0 + hi8);
  const float* amA = amax + (size_t)rowA * Kb + (k0 >> 6);
  const float* amB = amA + (size_t)16 * Kb;

  // packed-A stream: wave owns 128 rows = 8 m-blocks; advance 2 kb per kt.
  const __half* pA = Apk + ((size_t)((k0 >> 5) * 32 + wave * 8)) * 512
                         + (size_t)lane * 8;

  float4v acc[8][2];
  {
    float4v z = {0.f, 0.f, 0.f, 0.f};
    #pragma unroll
    for (int i = 0; i < 8; ++i)
      #pragma unroll
      for (int j = 0; j < 2; ++j) acc[i][j] = z;
  }

  int4  cq[8];       // next-kt codes: [j0kk0 x2][j0kk1 x2][j1kk0 x2][j1kk1 x2]
  float af[2];       // next-kt absmax (j=0, j=1)

#define LOADCQ()                                                                \
  { cq[0] = c4a[0]; cq[1] = c4a[1]; cq[2] = c4a[8]; cq[3] = c4a[9];             \
    cq[4] = c4b[0]; cq[5] = c4b[1]; cq[6] = c4b[8]; cq[7] = c4b[9];             \
    af[0] = *amA; af[1] = *amB;                                                 \
    c4a += 16; c4b += 16; ++amA; ++amB; }

// 8 codes (2 int4) + absmax half2 -> one half8 B-fragment (k-ascending)
#define DEQ1(DST, Q0, Q1, AM2)                                                  \
  { unsigned _w0 = ptab[Q0.x | (Q0.y << 4)];                                    \
    unsigned _w1 = ptab[Q0.z | (Q0.w << 4)];                                    \
    unsigned _w2 = ptab[Q1.x | (Q1.y << 4)];                                    \
    unsigned _w3 = ptab[Q1.z | (Q1.w << 4)];                                    \
    __half2 _p0 = __hmul2(*(const __half2*)&_w0, AM2);                          \
    __half2 _p1 = __hmul2(*(const __half2*)&_w1, AM2);                          \
    __half2 _p2 = __hmul2(*(const __half2*)&_w2, AM2);                          \
    __half2 _p3 = __hmul2(*(const __half2*)&_w3, AM2);                          \
    uint4 _wv;                                                                  \
    _wv.x = *(const unsigned*)&_p0; _wv.y = *(const unsigned*)&_p1;             \
    _wv.z = *(const unsigned*)&_p2; _wv.w = *(const unsigned*)&_p3;             \
    DST = *(const half8*)&_wv; }

  LOADCQ();                              // prologue: codes for kt=0

  for (int kt = 0; kt < nk; ++kt) {
    // dequant current kt from regs (frees cq for the next prefetch)
    const __half _a0 = __float2half(af[0]);
    const __half _a1 = __float2half(af[1]);
    const __half2 am20{_a0, _a0}, am21{_a1, _a1};
    half8 bq00, bq01, bq10, bq11;        // [j][kk]
    DEQ1(bq00, cq[0], cq[1], am20);
    DEQ1(bq01, cq[2], cq[3], am20);
    DEQ1(bq10, cq[4], cq[5], am21);
    DEQ1(bq11, cq[6], cq[7], am21);

    half8 ap[8];                         // A kk0 (L2)
    #pragma unroll
    for (int i = 0; i < 8; ++i)
      ap[i] = *(const half8*)(pA + i * 512);

    if (kt + 1 < nk) LOADCQ();           // HBM codes newest in vmcnt queue

    #pragma unroll
    for (int i = 0; i < 8; ++i) {        // waits A kk0; codes stay in flight
      acc[i][0] = __builtin_amdgcn_mfma_f32_16x16x32_f16(ap[i], bq00, acc[i][0], 0, 0, 0);
      acc[i][1] = __builtin_amdgcn_mfma_f32_16x16x32_f16(ap[i], bq10, acc[i][1], 0, 0, 0);
    }

    #pragma unroll
    for (int i = 0; i < 8; ++i)          // A kk1 (L2), reuses ap regs
      ap[i] = *(const half8*)(pA + 16384 + i * 512);

    #pragma unroll
    for (int i = 0; i < 8; ++i) {        // waits A kk1; codes stay in flight
      acc[i][0] = __builtin_amdgcn_mfma_f32_16x16x32_f16(ap[i], bq01, acc[i][0], 0, 0, 0);
      acc[i][1] = __builtin_amdgcn_mfma_f32_16x16x32_f16(ap[i], bq11, acc[i][1], 0, 0, 0);
    }

    pA += 32768;                         // 2 kb per kt
  }

  // ---- epilogue. C/D map: col = lane&15 (n), row = (lane>>4)*4 + reg (m)
  if (ATOMIC) {
    const int ccol0 = col0 + l15;
    const int crow0 = wave * 128 + ((lane >> 4) << 2);
    #pragma unroll
    for (int i = 0; i < 8; ++i)
      #pragma unroll
      for (int j = 0; j < 2; ++j)
        #pragma unroll
        for (int rr = 0; rr < 4; ++rr) {
          const size_t idx = (size_t)(crow0 + i * 16 + rr) * N + (ccol0 + j * 16);
          atomicAdd(&outF[idx], acc[i][j][rr]);
        }
  } else {
    // store C packed (m = token row, n = this GEMM's out col = down's K):
    //   (((n>>5)*32 + (m>>4))*64 + ((n>>3)&3)*16 + (m&15))*8 + (n&7)
    const int jj    = lane & 7;
    const int lb    = (lane >> 3) & 1;
    const int rbase = (lane >> 4) << 2;
    const int kb    = col0 >> 5;               // single 32-col block
    #pragma unroll
    for (int i = 0; i < 8; ++i) {
      const int mb = wave * 8 + i;
      #pragma unroll
      for (int j = 0; j < 2; ++j) {
        const int lp = (j * 2 + lb) * 16 + rbase;
        #pragma unroll
        for (int rr = 0; rr < 4; ++rr) {
          const size_t a = ((size_t)(kb * 32 + mb) * 64 + (lp + rr)) * 8 + jj;
          outH[a] = __float2half(acc[i][j][rr]);
        }
      }
    }
  }
#undef LOADCQ
#undef DEQ1
}

// x fp32 row-major [512][4096] -> packed f16 fragment layout.
__global__ void cast_pack_kernel(const float* __restrict__ x,
                                 __half* __restrict__ xp, int nGrp) {
  int pid = blockIdx.x * blockDim.x + threadIdx.x;   // one per 8 halfs
  if (pid >= nGrp) return;
  const int lane = pid & 63;
  const int grp  = pid >> 6;
  const int mb   = grp & 31;          // M=512 -> 32 m-tiles
  const int kb   = grp >> 5;
  const int m = mb * 16 + (lane & 15);
  const int k = kb * 32 + ((lane >> 4) << 3);
  const float4* src = (const float4*)(x + (size_t)m * 4096 + k);
  float4 v0 = src[0], v1 = src[1];
  __half2 h0 = __floats2half2_rn(v0.x, v0.y), h1 = __floats2half2_rn(v0.z, v0.w);
  __half2 h2 = __floats2half2_rn(v1.x, v1.y), h3 = __floats2half2_rn(v1.z, v1.w);
  uint4 o;
  o.x = *(const unsigned*)&h0; o.y = *(const unsigned*)&h1;
  o.z = *(const unsigned*)&h2; o.w = *(const unsigned*)&h3;
  ((uint4*)xp)[pid] = o;
}

// elementwise silu(g)*u — layout-agnostic (g,u share the packed layout).
__global__ void swiglu_kernel(const __half* __restrict__ g,
                              const __half* __restrict__ u,
                              __half* __restrict__ h, int n2) {
  int i = blockIdx.x * blockDim.x + threadIdx.x;
  if (i < n2) {
    float2 gf = __half22float2(((const __half2*)g)[i]);
    float2 uf = __half22float2(((const __half2*)u)[i]);
    float h0 = gf.x / (1.f + __expf(-gf.x)) * uf.x;
    float h1 = gf.y / (1.f + __expf(-gf.y)) * uf.y;
    ((__half2*)h)[i] = __floats2half2_rn(h0, h1);
  }
}

extern "C" void kernel_launch(void* const* d_in, const int* in_sizes, int n_in,
                              void* d_out, int out_size, void* d_ws, size_t ws_size,
                              hipStream_t stream)
{
  (void)in_sizes; (void)n_in; (void)ws_size;
  const float* x            = (const float*)d_in[0];
  const int*   gate_codes   = (const int*)d_in[1];
  const float* gate_absmax  = (const float*)d_in[2];
  const int*   up_codes     = (const int*)d_in[3];
  const float* up_absmax    = (const float*)d_in[4];
  const int*   down_codes   = (const int*)d_in[5];
  const float* down_absmax  = (const float*)d_in[6];
  float* out = (float*)d_out;

  // ws: xp 4MB | g 11.3MB | u 11.3MB   (h = silu(g)*u written in place over g)
  __half* xp = (__half*)d_ws;
  __half* g  = xp + (size_t)512 * 4096;
  __half* u  = g  + (size_t)512 * 11008;

  hipMemsetAsync(d_out, 0, (size_t)out_size * sizeof(float), stream);

  cast_pack_kernel<<<1024, 256, 0, stream>>>(x, xp, (512 * 4096) / 8);

  // fused gate+up: 344 Ntiles x 2 mats = 688 blocks (full M per block)
  gemm_nf4<false><<<688, 256, 0, stream>>>(xp, gate_codes, gate_absmax,
                                           up_codes, up_absmax,
                                           g, u, nullptr,
                                           11008, 4096, 4096, 344);

  swiglu_kernel<<<11008, 256, 0, stream>>>(g, u, g, (512 * 11008) / 2);

  // down: out += h * Wd^T, split-K=4: 128 Ntiles x 4 = 512 blocks
  gemm_nf4<true><<<512, 256, 0, stream>>>(g, down_codes, down_absmax,
                                          nullptr, nullptr, nullptr, nullptr,
                                          out, 4096, 11008, 2752, 128);
}

// Round 7
// 810.867 us; speedup vs baseline: 1.0982x; 1.0982x over previous
//
#include <hip/hip_runtime.h>
#include <hip/hip_fp16.h>
#include <cstdint>
#include <cstddef>

// x[512,4096] fp32 ; gate/up codes [11008,4096] i32 ; down codes [4096,11008] i32
// absmax blocks of 64 along K ; out [512,4096] fp32
//
// R10 (resubmit #1 — GPUAcquisitionTimeout, never ran):
// offline nibble-repack + barrier-free packed GEMM:
//  - R6-R8 pinned at ~230us/GEMM while hbm_bytes varied 417->237MB (BW moved
//    with bytes, time didn't): not bytes-bound. ~22k concurrent 256B-granular
//    code streams -> DRAM row-locality/queueing collapse (implied effective
//    latency ~17k cyc). R9 (barrier-free, gathered loads) made it worse.
//  - Repack pass: codes int32 -> packed nibbles in GEMM-native layout:
//    per (tile,kb): 64 lanes x 16B, lane's dwordx4 = its 4 B-fragments
//    (d0=j0kk0,d1=j0kk1,d2=j1kk0,d3=j1kk1; byte=k-pair, ptab index direct).
//    absmax repacked to [tile][kb][32] f32. Packed total 67MB+8.5MB =
//    L3-resident; GEMM reads ONE dwordx4/lane/kt (1KB/wave, L1-shared x4).
//  - GEMM: R8 geometry (full-M 512x32N, 4 waves, acc[8][2]), NO loop barrier,
//    codes prefetched 1 kt ahead (vmcnt aging: A kk0 issued before next-codes,
//    MFMA's wait retires A, leaves codes in flight). ~139 regs -> 3 waves/SIMD.

using float4v = __attribute__((ext_vector_type(4))) float;
using half8   = __attribute__((ext_vector_type(8))) _Float16;

__constant__ float NF4TAB[16] = {
  -1.0f, -0.6961928009986877f, -0.5250730514526367f, -0.39491748809814453f,
  -0.28444138169288635f, -0.18477343022823334f, -0.09105003625154495f, 0.0f,
  0.07958029955625534f, 0.16093020141124725f, 0.24611230194568634f,
  0.33791524171829224f, 0.44070982933044434f, 0.5626170039176941f,
  0.7229568362236023f, 1.0f };

// Packed A layout (M=512 fixed): element (m,k) at
//   (((k>>5)*32 + (m>>4))*64 + ((k>>3)&3)*16 + (m&15))*8 + (k&7)
// -> frag (mb,kb): 64 lanes x 16B dense at (kb*32+mb)*512 + lane*8.

// ---------------------------------------------------------------------------
// repack: codes[N][K] i32 (values 0..15) + amax[N][Kb] f32 ->
//   outp[tile][kb][lane(64)][16B], outam[tile][kb][32] f32
// tile = 32 N-rows. Block = 256 thr = 4 waves; wave w handles kb = kbg*4+w.
// Per wave: read 32 rows x 64 ints (8 instrs, each 4 rows x 256B contiguous),
// pack int4->ushort into LDS [32][36B] (pad 36 -> conflict-free-ish), then
// lane emits its dwordx4: {row l15 kk0, row l15 kk1, row l15+16 kk0, kk1}.
// Wave-self-contained: no __syncthreads (cross-lane via lgkmcnt(0) only).
__global__ __launch_bounds__(256) void repack_kernel(
    const int* __restrict__ codes, const float* __restrict__ amax,
    unsigned char* __restrict__ outp, float* __restrict__ outam,
    int K, int Kb, int KbG)
{
  __shared__ unsigned char lds[4][32 * 36];
  const int tid  = threadIdx.x;
  const int lane = tid & 63;
  const int w    = tid >> 6;
  const int l15  = lane & 15;
  const int hi   = lane >> 4;

  const int bid  = blockIdx.x;
  const int tile = bid / KbG;
  const int kb   = (bid % KbG) * 4 + w;

  const int* src = codes + (size_t)tile * 32 * K + (size_t)kb * 64;

  #pragma unroll
  for (int i = 0; i < 8; ++i) {
    const int row = i * 4 + hi;
    const int4 c = *(const int4*)(src + (size_t)row * K + l15 * 4);
    const unsigned short v =
      (unsigned short)((c.x | (c.y << 4)) | ((c.z | (c.w << 4)) << 8));
    *(unsigned short*)&lds[w][row * 36 + l15 * 2] = v;
  }
  asm volatile("s_waitcnt lgkmcnt(0)" ::: "memory");
  __builtin_amdgcn_sched_barrier(0);

  uint4 o;
  o.x = *(const unsigned*)&lds[w][l15 * 36 + hi * 4];            // j0 kk0
  o.y = *(const unsigned*)&lds[w][l15 * 36 + 16 + hi * 4];       // j0 kk1
  o.z = *(const unsigned*)&lds[w][(l15 + 16) * 36 + hi * 4];     // j1 kk0
  o.w = *(const unsigned*)&lds[w][(l15 + 16) * 36 + 16 + hi * 4];// j1 kk1
  *(uint4*)(outp + (((size_t)tile * Kb + kb) * 64 + lane) * 16) = o;

  if (lane < 32)
    outam[((size_t)tile * Kb + kb) * 32 + lane] =
      amax[(size_t)(tile * 32 + lane) * Kb + kb];
}

// ---------------------------------------------------------------------------
// C[512 x N] = A_packed * dequant(packed codes)^T
// Block 512M x 32N, BK=64, 4 waves, wave tile 128x32 (8x2 MFMA 16x16x32 f16).
// B-operand (16x16x32): lane holds B[k=kk*32+(lane>>4)*8+e][n=lane&15].
// ATOMIC=false: r2 selects gate/up matrix; C stored f16 PACKED.
// ATOMIC=true : r2 = K-chunk (split-K); fp32 atomicAdd into row-major outF.
template <bool ATOMIC>
__global__ __launch_bounds__(256, 3) void gemm_nf4(
    const __half* __restrict__ Apk,
    const unsigned char* __restrict__ p0, const float* __restrict__ am0,
    const unsigned char* __restrict__ p1, const float* __restrict__ am1,
    __half* __restrict__ o0, __half* __restrict__ o1,
    float* __restrict__ outF,
    int N, int K, int Kc, int Ntiles)
{
  __shared__ unsigned ptab[256];         // packed f16 pair {tab[lo],tab[hi]}

  const int tid  = threadIdx.x;
  const int lane = tid & 63;
  const int wave = tid >> 6;
  const int l15  = lane & 15;

  {
    __half2 pr = __floats2half2_rn(NF4TAB[tid & 15], NF4TAB[tid >> 4]);
    ptab[tid] = *(const unsigned*)&pr;
  }
  __syncthreads();                       // ptab visible; ONLY barrier.

  int nt, r2;
  if (ATOMIC) {
    // Pin each K-chunk to an XCD pair so its A-slice stays in that L2.
    const int xcd  = blockIdx.x & 7;
    const int slot = blockIdx.x >> 3;            // 0..63
    r2 = xcd >> 1;                               // K-chunk 0..3
    nt = (xcd & 1) * (Ntiles >> 1) + slot;       // 0..127
  } else {
    const int nwg = gridDim.x;
    const int bid = (blockIdx.x & 7) * (nwg >> 3) + (blockIdx.x >> 3);
    nt = bid % Ntiles;
    r2 = bid / Ntiles;                           // matrix select
  }

  const int k0 = ATOMIC ? r2 * Kc : 0;
  const int nk = Kc >> 6;
  const unsigned char* pk = (!ATOMIC && r2) ? p1 : p0;
  const float* amx        = (!ATOMIC && r2) ? am1 : am0;
  __half* outH            = (!ATOMIC && r2) ? o1 : o0;

  const int col0 = nt * 32;
  const int Kb   = K >> 6;
  const int kb0q = k0 >> 6;

  // packed code/absmax streams (1KB & 128B per kt per block, L1-shared x4)
  const uint4* pc  = (const uint4*)(pk + (((size_t)nt * Kb + kb0q) * 64 + lane) * 16);
  const float* pam = amx + ((size_t)nt * Kb + kb0q) * 32 + l15;

  // packed-A stream: wave owns 128 rows = 8 m-blocks; advance 2 kb per kt.
  const __half* pA = Apk + ((size_t)((k0 >> 5) * 32 + wave * 8)) * 512
                         + (size_t)lane * 8;

  float4v acc[8][2];
  {
    float4v z = {0.f, 0.f, 0.f, 0.f};
    #pragma unroll
    for (int i = 0; i < 8; ++i)
      #pragma unroll
      for (int j = 0; j < 2; ++j) acc[i][j] = z;
  }

  uint4 cq;          // next-kt packed codes (16B)
  float af[2];       // next-kt absmax (j=0, j=1)

#define LOADCQ()                                                                \
  { cq = *pc; af[0] = pam[0]; af[1] = pam[16];                                  \
    pc += 64; pam += 32; }

// one dword (4 packed bytes) + absmax half2 -> one half8 B-fragment
#define DEQD(DST, D, AM2)                                                       \
  { unsigned _w0 = ptab[(D) & 255];                                             \
    unsigned _w1 = ptab[((D) >> 8) & 255];                                      \
    unsigned _w2 = ptab[((D) >> 16) & 255];                                     \
    unsigned _w3 = ptab[(D) >> 24];                                             \
    __half2 _p0 = __hmul2(*(const __half2*)&_w0, AM2);                          \
    __half2 _p1 = __hmul2(*(const __half2*)&_w1, AM2);                          \
    __half2 _p2 = __hmul2(*(const __half2*)&_w2, AM2);                          \
    __half2 _p3 = __hmul2(*(const __half2*)&_w3, AM2);                          \
    uint4 _wv;                                                                  \
    _wv.x = *(const unsigned*)&_p0; _wv.y = *(const unsigned*)&_p1;             \
    _wv.z = *(const unsigned*)&_p2; _wv.w = *(const unsigned*)&_p3;             \
    DST = *(const half8*)&_wv; }

  LOADCQ();                              // prologue: codes for kt=0

  for (int kt = 0; kt < nk; ++kt) {
    // dequant current kt from regs (frees cq for the next prefetch)
    const __half _a0 = __float2half(af[0]);
    const __half _a1 = __float2half(af[1]);
    const __half2 am20{_a0, _a0}, am21{_a1, _a1};
    half8 bq00, bq01, bq10, bq11;        // [j][kk]
    DEQD(bq00, cq.x, am20);
    DEQD(bq01, cq.y, am20);
    DEQD(bq10, cq.z, am21);
    DEQD(bq11, cq.w, am21);

    half8 ap[8];                         // A kk0 (L2)
    #pragma unroll
    for (int i = 0; i < 8; ++i)
      ap[i] = *(const half8*)(pA + i * 512);

    if (kt + 1 < nk) LOADCQ();           // codes newest in vmcnt queue

    #pragma unroll
    for (int i = 0; i < 8; ++i) {        // waits A kk0; codes stay in flight
      acc[i][0] = __builtin_amdgcn_mfma_f32_16x16x32_f16(ap[i], bq00, acc[i][0], 0, 0, 0);
      acc[i][1] = __builtin_amdgcn_mfma_f32_16x16x32_f16(ap[i], bq10, acc[i][1], 0, 0, 0);
    }

    #pragma unroll
    for (int i = 0; i < 8; ++i)          // A kk1 (L2), reuses ap regs
      ap[i] = *(const half8*)(pA + 16384 + i * 512);

    #pragma unroll
    for (int i = 0; i < 8; ++i) {        // waits A kk1; codes stay in flight
      acc[i][0] = __builtin_amdgcn_mfma_f32_16x16x32_f16(ap[i], bq01, acc[i][0], 0, 0, 0);
      acc[i][1] = __builtin_amdgcn_mfma_f32_16x16x32_f16(ap[i], bq11, acc[i][1], 0, 0, 0);
    }

    pA += 32768;                         // 2 kb per kt
  }

  // ---- epilogue. C/D map: col = lane&15 (n), row = (lane>>4)*4 + reg (m)
  if (ATOMIC) {
    const int ccol0 = col0 + l15;
    const int crow0 = wave * 128 + ((lane >> 4) << 2);
    #pragma unroll
    for (int i = 0; i < 8; ++i)
      #pragma unroll
      for (int j = 0; j < 2; ++j)
        #pragma unroll
        for (int rr = 0; rr < 4; ++rr) {
          const size_t idx = (size_t)(crow0 + i * 16 + rr) * N + (ccol0 + j * 16);
          atomicAdd(&outF[idx], acc[i][j][rr]);
        }
  } else {
    // store C packed (m = token row, n = this GEMM's out col = down's K):
    //   (((n>>5)*32 + (m>>4))*64 + ((n>>3)&3)*16 + (m&15))*8 + (n&7)
    const int jj    = lane & 7;
    const int lb    = (lane >> 3) & 1;
    const int rbase = (lane >> 4) << 2;
    const int kb    = col0 >> 5;               // single 32-col block
    #pragma unroll
    for (int i = 0; i < 8; ++i) {
      const int mb = wave * 8 + i;
      #pragma unroll
      for (int j = 0; j < 2; ++j) {
        const int lp = (j * 2 + lb) * 16 + rbase;
        #pragma unroll
        for (int rr = 0; rr < 4; ++rr) {
          const size_t a = ((size_t)(kb * 32 + mb) * 64 + (lp + rr)) * 8 + jj;
          outH[a] = __float2half(acc[i][j][rr]);
        }
      }
    }
  }
#undef LOADCQ
#undef DEQD
}

// x fp32 row-major [512][4096] -> packed f16 fragment layout.
__global__ void cast_pack_kernel(const float* __restrict__ x,
                                 __half* __restrict__ xp, int nGrp) {
  int pid = blockIdx.x * blockDim.x + threadIdx.x;   // one per 8 halfs
  if (pid >= nGrp) return;
  const int lane = pid & 63;
  const int grp  = pid >> 6;
  const int mb   = grp & 31;          // M=512 -> 32 m-tiles
  const int kb   = grp >> 5;
  const int m = mb * 16 + (lane & 15);
  const int k = kb * 32 + ((lane >> 4) << 3);
  const float4* src = (const float4*)(x + (size_t)m * 4096 + k);
  float4 v0 = src[0], v1 = src[1];
  __half2 h0 = __floats2half2_rn(v0.x, v0.y), h1 = __floats2half2_rn(v0.z, v0.w);
  __half2 h2 = __floats2half2_rn(v1.x, v1.y), h3 = __floats2half2_rn(v1.z, v1.w);
  uint4 o;
  o.x = *(const unsigned*)&h0; o.y = *(const unsigned*)&h1;
  o.z = *(const unsigned*)&h2; o.w = *(const unsigned*)&h3;
  ((uint4*)xp)[pid] = o;
}

// elementwise silu(g)*u — layout-agnostic (g,u share the packed layout).
__global__ void swiglu_kernel(const __half* __restrict__ g,
                              const __half* __restrict__ u,
                              __half* __restrict__ h, int n2) {
  int i = blockIdx.x * blockDim.x + threadIdx.x;
  if (i < n2) {
    float2 gf = __half22float2(((const __half2*)g)[i]);
    float2 uf = __half22float2(((const __half2*)u)[i]);
    float h0 = gf.x / (1.f + __expf(-gf.x)) * uf.x;
    float h1 = gf.y / (1.f + __expf(-gf.y)) * uf.y;
    ((__half2*)h)[i] = __floats2half2_rn(h0, h1);
  }
}

extern "C" void kernel_launch(void* const* d_in, const int* in_sizes, int n_in,
                              void* d_out, int out_size, void* d_ws, size_t ws_size,
                              hipStream_t stream)
{
  (void)in_sizes; (void)n_in; (void)ws_size;
  const float* x            = (const float*)d_in[0];
  const int*   gate_codes   = (const int*)d_in[1];
  const float* gate_absmax  = (const float*)d_in[2];
  const int*   up_codes     = (const int*)d_in[3];
  const float* up_absmax    = (const float*)d_in[4];
  const int*   down_codes   = (const int*)d_in[5];
  const float* down_absmax  = (const float*)d_in[6];
  float* out = (float*)d_out;

  // ws layout (bytes):
  //  xp 4.19MB | g 11.27MB | u 11.27MB |
  //  pg 22.5MB | pu 22.5MB | pd 22.5MB | amg 2.82MB | amu 2.82MB | amd 2.82MB
  __half* xp = (__half*)d_ws;
  __half* g  = xp + (size_t)512 * 4096;
  __half* u  = g  + (size_t)512 * 11008;
  unsigned char* pg = (unsigned char*)(u + (size_t)512 * 11008);
  unsigned char* pu = pg + (size_t)344 * 64 * 1024;
  unsigned char* pd = pu + (size_t)344 * 64 * 1024;
  float* amg = (float*)(pd + (size_t)128 * 172 * 1024);
  float* amu = amg + (size_t)344 * 64 * 32;
  float* amd = amu + (size_t)344 * 64 * 32;

  hipMemsetAsync(d_out, 0, (size_t)out_size * sizeof(float), stream);

  cast_pack_kernel<<<1024, 256, 0, stream>>>(x, xp, (512 * 4096) / 8);

  // repack: gate/up (344 tiles x Kb=64 -> 5504 blocks), down (128 x 172 -> 5504)
  repack_kernel<<<5504, 256, 0, stream>>>(gate_codes, gate_absmax, pg, amg,
                                          4096, 64, 16);
  repack_kernel<<<5504, 256, 0, stream>>>(up_codes, up_absmax, pu, amu,
                                          4096, 64, 16);
  repack_kernel<<<5504, 256, 0, stream>>>(down_codes, down_absmax, pd, amd,
                                          11008, 172, 43);

  // fused gate+up: 344 Ntiles x 2 mats = 688 blocks (full M per block)
  gemm_nf4<false><<<688, 256, 0, stream>>>(xp, pg, amg, pu, amu,
                                           g, u, nullptr,
                                           11008, 4096, 4096, 344);

  swiglu_kernel<<<11008, 256, 0, stream>>>(g, u, g, (512 * 11008) / 2);

  // down: out += h * Wd^T, split-K=4: 128 Ntiles x 4 = 512 blocks
  gemm_nf4<true><<<512, 256, 0, stream>>>(g, pd, amd,
                                          nullptr, nullptr, nullptr, nullptr,
                                          out, 4096, 11008, 2752, 128);
}

// Round 8
// 705.279 us; speedup vs baseline: 1.2626x; 1.1497x over previous
//
#include <hip/hip_runtime.h>
#include <hip/hip_fp16.h>
#include <cstdint>
#include <cstddef>

// x[512,4096] fp32 ; gate/up codes [11008,4096] i32 ; down codes [4096,11008] i32
// absmax blocks of 64 along K ; out [512,4096] fp32
//
// R11 = A-L2-congestion attack + register-only repack:
//  - R10 post-mortem: FETCH 206->41MB, time 233->212us. Not bytes-bound.
//    But: per-dispatch L2 A-traffic = 688 blocks x 4MB = 2.75GB; 2.75GB/212us
//    = 13 TB/s = effective L2 ceiling for lockstep hot-window reads. That's
//    the wall (R8: 2.75GB/233 = 11.8 TB/s, same).
//  - Fix 1: BM 512->256, BN 32->64. Same block counts (688/512), same
//    acc[4][4] budget, A L2-traffic halved to 1.37GB. Codes (packed, L3) get
//    2x replicated - cheap. Codes prefetched 2-kt-deep in 2 STATIC slots so
//    consumption is always >=1 full iter aged (vmcnt retire order safe).
//  - Fix 2: repack with NO LDS: lane assembles exactly the uint4 pair its
//    GEMM twin-lane reads: 16 dense int4 loads (each instr = 32 full 64B
//    lines), ~60 VALU pack ops, one 32B coalesced store. absmax via float4
//    read + 4 coalesced stores (wave 0). R10's repack (LDS transpose) was
//    370us for 3 passes; this should be ~95-120us (HBM streaming bound).
//  - GEMM stays barrier-free (R10 beat R8's barrier version), ptab LDS
//    pair-table dequant, launch_bounds(256,3).

using float4v = __attribute__((ext_vector_type(4))) float;
using half8   = __attribute__((ext_vector_type(8))) _Float16;

__constant__ float NF4TAB[16] = {
  -1.0f, -0.6961928009986877f, -0.5250730514526367f, -0.39491748809814453f,
  -0.28444138169288635f, -0.18477343022823334f, -0.09105003625154495f, 0.0f,
  0.07958029955625534f, 0.16093020141124725f, 0.24611230194568634f,
  0.33791524171829224f, 0.44070982933044434f, 0.5626170039176941f,
  0.7229568362236023f, 1.0f };

// Packed A layout (M=512 fixed): element (m,k) at
//   (((k>>5)*32 + (m>>4))*64 + ((k>>3)&3)*16 + (m&15))*8 + (k&7)
// -> frag (mb,kb): 64 lanes x 16B dense at (kb*32+mb)*512 + lane*8.

// ---------------------------------------------------------------------------
// repack: codes[Nrows][K] i32 (0..15) + amax[Nrows][Kb] f32 ->
//   pb[tile][kb][lane][2xuint4], pam[tile][kb][64] f32     (tile = 64 rows)
// uint4 #0 = {j0kk0, j0kk1, j1kk0, j1kk1}, #1 = {j2kk0,...}: dword jXkkY =
//   row tile*64 + X*16 + l15, octet Y*4 + hi of the kb 64-k window
//   (byte b: lo nibble = code k=2b, hi nibble = k=2b+1, k ascending).
// Block = (tile, kbg of 4 kbs); wave w -> kb = kbg*4 + w. No LDS.
__global__ __launch_bounds__(256) void repack_kernel(
    const int* __restrict__ codes, const float* __restrict__ amax,
    unsigned char* __restrict__ pb, float* __restrict__ pam,
    int K, int Kb, int KbG)
{
  const int tid  = threadIdx.x;
  const int lane = tid & 63;
  const int w    = tid >> 6;
  const int l15  = lane & 15;
  const int hi   = lane >> 4;

  const int tile = blockIdx.x / KbG;
  const int kbg  = blockIdx.x % KbG;
  const int kb   = kbg * 4 + w;

  unsigned dk0[4], dk1[4];
  #pragma unroll
  for (int j = 0; j < 4; ++j) {
    const int* base = codes + (size_t)(tile * 64 + j * 16 + l15) * K
                            + (size_t)kb * 64;
    const int4 a0 = *(const int4*)(base + hi * 8);
    const int4 a1 = *(const int4*)(base + hi * 8 + 4);
    const int4 b0 = *(const int4*)(base + 32 + hi * 8);
    const int4 b1 = *(const int4*)(base + 32 + hi * 8 + 4);
    dk0[j] = (unsigned)((a0.x | (a0.y << 4)) | ((a0.z | (a0.w << 4)) << 8) |
                        ((a1.x | (a1.y << 4)) << 16) | ((a1.z | (a1.w << 4)) << 24));
    dk1[j] = (unsigned)((b0.x | (b0.y << 4)) | ((b0.z | (b0.w << 4)) << 8) |
                        ((b1.x | (b1.y << 4)) << 16) | ((b1.z | (b1.w << 4)) << 24));
  }
  uint4 o0, o1;
  o0.x = dk0[0]; o0.y = dk1[0]; o0.z = dk0[1]; o0.w = dk1[1];
  o1.x = dk0[2]; o1.y = dk1[2]; o1.z = dk0[3]; o1.w = dk1[3];
  uint4* dst = (uint4*)(pb + (((size_t)tile * Kb + kb) * 64 + lane) * 32);
  dst[0] = o0; dst[1] = o1;

  if (w == 0) {                         // absmax: rows tile*64+lane, kbs kbg*4..+3
    const float4 am = *(const float4*)(amax + (size_t)(tile * 64 + lane) * Kb
                                            + kbg * 4);
    pam[((size_t)tile * Kb + kbg * 4 + 0) * 64 + lane] = am.x;
    pam[((size_t)tile * Kb + kbg * 4 + 1) * 64 + lane] = am.y;
    pam[((size_t)tile * Kb + kbg * 4 + 2) * 64 + lane] = am.z;
    pam[((size_t)tile * Kb + kbg * 4 + 3) * 64 + lane] = am.w;
  }
}

// ---------------------------------------------------------------------------
// C[512 x N] = A_packed * dequant(packed codes)^T
// Block 256M x 64N, BK=64, 4 waves, wave tile 64x64 (4x4 MFMA 16x16x32 f16).
// B-operand (16x16x32): lane holds B[k=kk*32+(lane>>4)*8+e][n=lane&15].
// ATOMIC=false: r2 selects gate/up matrix; C stored f16 PACKED.
// ATOMIC=true : r2 = K-chunk (split-K); fp32 atomicAdd into row-major outF.
template <bool ATOMIC>
__global__ __launch_bounds__(256, 3) void gemm_nf4(
    const __half* __restrict__ Apk,
    const unsigned char* __restrict__ p0, const float* __restrict__ am0,
    const unsigned char* __restrict__ p1, const float* __restrict__ am1,
    __half* __restrict__ o0, __half* __restrict__ o1,
    float* __restrict__ outF,
    int N, int K, int Kc, int Ntiles)
{
  __shared__ unsigned ptab[256];         // packed f16 pair {tab[lo],tab[hi]}

  const int tid  = threadIdx.x;
  const int lane = tid & 63;
  const int wave = tid >> 6;
  const int l15  = lane & 15;

  {
    __half2 pr = __floats2half2_rn(NF4TAB[tid & 15], NF4TAB[tid >> 4]);
    ptab[tid] = *(const unsigned*)&pr;
  }
  __syncthreads();                       // ptab visible; ONLY barrier.

  int nt, r2, mt;
  if (ATOMIC) {
    // Pin each K-chunk to an XCD pair so its A-slice stays in that L2.
    const int xcd  = blockIdx.x & 7;
    const int slot = blockIdx.x >> 3;            // 0..63
    r2 = xcd >> 1;                               // K-chunk 0..3
    mt = slot & 1;
    nt = (slot >> 1) + (xcd & 1) * 32;           // 0..63
  } else {
    const int nwg = gridDim.x;
    const int bid = (blockIdx.x & 7) * (nwg >> 3) + (blockIdx.x >> 3);
    mt = bid & 1;
    const int r = bid >> 1;
    nt = r % Ntiles;
    r2 = r / Ntiles;                             // matrix select
  }

  const int k0 = ATOMIC ? r2 * Kc : 0;
  const int nk = Kc >> 6;
  const unsigned char* pk = (!ATOMIC && r2) ? p1 : p0;
  const float* amx        = (!ATOMIC && r2) ? am1 : am0;
  __half* outH            = (!ATOMIC && r2) ? o1 : o0;

  const int col0 = nt * 64;
  const int Kb   = K >> 6;
  const int kb0q = k0 >> 6;

  // packed code/absmax streams: 2 uint4 + 4 floats per lane per kt
  const uint4* pc  = (const uint4*)(pk + (((size_t)nt * Kb + kb0q) * 64 + lane) * 32);
  const float* pam = amx + ((size_t)nt * Kb + kb0q) * 64 + l15;

  // packed-A stream: wave owns 64 rows = 4 m-blocks; advance 2 kb per kt.
  const int mb0 = mt * 16 + wave * 4;
  const __half* pA = Apk + ((size_t)((k0 >> 5) * 32 + mb0) * 512)
                         + (size_t)lane * 8;

  float4v acc[4][4];
  {
    float4v z = {0.f, 0.f, 0.f, 0.f};
    #pragma unroll
    for (int i = 0; i < 4; ++i)
      #pragma unroll
      for (int j = 0; j < 4; ++j) acc[i][j] = z;
  }

  // 2-deep code prefetch, STATIC slots (R4 lesson: no runtime slot index)
  uint4 q0_0, q1_0, q0_1, q1_1;
  float af_0[4], af_1[4];

#define LOADCQ0(KT)                                                             \
  { const uint4* _p = pc + (size_t)(KT) * 128;                                  \
    q0_0 = _p[0]; q1_0 = _p[1];                                                 \
    const float* _a = pam + (size_t)(KT) * 64;                                  \
    af_0[0] = _a[0]; af_0[1] = _a[16]; af_0[2] = _a[32]; af_0[3] = _a[48]; }
#define LOADCQ1(KT)                                                             \
  { const uint4* _p = pc + (size_t)(KT) * 128;                                  \
    q0_1 = _p[0]; q1_1 = _p[1];                                                 \
    const float* _a = pam + (size_t)(KT) * 64;                                  \
    af_1[0] = _a[0]; af_1[1] = _a[16]; af_1[2] = _a[32]; af_1[3] = _a[48]; }

// one dword (4 packed bytes) + absmax half2 -> one half8 B-fragment
#define DEQD(DST, D, AM2)                                                       \
  { unsigned _w0 = ptab[(D) & 255];                                             \
    unsigned _w1 = ptab[((D) >> 8) & 255];                                      \
    unsigned _w2 = ptab[((D) >> 16) & 255];                                     \
    unsigned _w3 = ptab[(D) >> 24];                                             \
    __half2 _p0 = __hmul2(*(const __half2*)&_w0, AM2);                          \
    __half2 _p1 = __hmul2(*(const __half2*)&_w1, AM2);                          \
    __half2 _p2 = __hmul2(*(const __half2*)&_w2, AM2);                          \
    __half2 _p3 = __hmul2(*(const __half2*)&_w3, AM2);                          \
    uint4 _wv;                                                                  \
    _wv.x = *(const unsigned*)&_p0; _wv.y = *(const unsigned*)&_p1;             \
    _wv.z = *(const unsigned*)&_p2; _wv.w = *(const unsigned*)&_p3;             \
    DST = *(const half8*)&_wv; }

// BODY: codes for KT in slot S regs (aged >= 1 full iter). Issue order:
// DEQ kk0 (VALU+LDS) -> A kk0 (L2) -> MFMA kk0 (vmcnt retires A kk0 and
// anything older - all aged) -> DEQ kk1 -> A kk1 -> MFMA kk1 -> code loads
// for KT+2 issued LAST (newest; never force-drained before aging).
#define BODY(KT, S)                                                             \
  { half8 bq[4], ap[4];                                                         \
    { const __half _a0 = __float2half(af_##S[0]);                               \
      const __half _a1 = __float2half(af_##S[1]);                               \
      const __half _a2 = __float2half(af_##S[2]);                               \
      const __half _a3 = __float2half(af_##S[3]);                               \
      const __half2 _m0{_a0,_a0}, _m1{_a1,_a1}, _m2{_a2,_a2}, _m3{_a3,_a3};     \
      DEQD(bq[0], q0_##S.x, _m0); DEQD(bq[1], q0_##S.z, _m1);                   \
      DEQD(bq[2], q1_##S.x, _m2); DEQD(bq[3], q1_##S.z, _m3);                   \
      _Pragma("unroll")                                                         \
      for (int _i = 0; _i < 4; ++_i)                                            \
        ap[_i] = *(const half8*)(pA + (size_t)(KT) * 32768 + _i * 512);         \
      _Pragma("unroll")                                                         \
      for (int _i = 0; _i < 4; ++_i)                                            \
        _Pragma("unroll")                                                       \
        for (int _j = 0; _j < 4; ++_j)                                          \
          acc[_i][_j] = __builtin_amdgcn_mfma_f32_16x16x32_f16(ap[_i], bq[_j], acc[_i][_j], 0, 0, 0); \
      DEQD(bq[0], q0_##S.y, _m0); DEQD(bq[1], q0_##S.w, _m1);                   \
      DEQD(bq[2], q1_##S.y, _m2); DEQD(bq[3], q1_##S.w, _m3);                   \
      _Pragma("unroll")                                                         \
      for (int _i = 0; _i < 4; ++_i)                                            \
        ap[_i] = *(const half8*)(pA + (size_t)(KT) * 32768 + 16384 + _i * 512); \
      _Pragma("unroll")                                                         \
      for (int _i = 0; _i < 4; ++_i)                                            \
        _Pragma("unroll")                                                       \
        for (int _j = 0; _j < 4; ++_j)                                          \
          acc[_i][_j] = __builtin_amdgcn_mfma_f32_16x16x32_f16(ap[_i], bq[_j], acc[_i][_j], 0, 0, 0); \
    }                                                                           \
    if ((KT) + 2 < nk) { LOADCQ##S((KT) + 2); } }

  LOADCQ0(0);
  if (nk > 1) LOADCQ1(1);

  int kt = 0;
  while (kt + 2 <= nk) { BODY(kt, 0); BODY(kt + 1, 1); kt += 2; }
  if (kt < nk) BODY(kt, 0);            // odd-nk tail (down: nk=43)

  // ---- epilogue. C/D map: col = lane&15 (n), row = (lane>>4)*4 + reg (m)
  if (ATOMIC) {
    const int ccol0 = col0 + l15;
    const int crow0 = mt * 256 + wave * 64 + ((lane >> 4) << 2);
    #pragma unroll
    for (int i = 0; i < 4; ++i)
      #pragma unroll
      for (int j = 0; j < 4; ++j)
        #pragma unroll
        for (int rr = 0; rr < 4; ++rr) {
          const size_t idx = (size_t)(crow0 + i * 16 + rr) * N + (ccol0 + j * 16);
          atomicAdd(&outF[idx], acc[i][j][rr]);
        }
  } else {
    // store C packed (m = token row, n = this GEMM's out col = down's K):
    //   (((n>>5)*32 + (m>>4))*64 + ((n>>3)&3)*16 + (m&15))*8 + (n&7)
    const int jj    = lane & 7;
    const int lb    = (lane >> 3) & 1;
    const int rbase = (lane >> 4) << 2;
    #pragma unroll
    for (int i = 0; i < 4; ++i) {
      const int mb = mb0 + i;
      #pragma unroll
      for (int j = 0; j < 4; ++j) {
        const int kb = nt * 2 + (j >> 1);
        const int lp = ((j & 1) * 2 + lb) * 16 + rbase;
        #pragma unroll
        for (int rr = 0; rr < 4; ++rr) {
          const size_t a = ((size_t)(kb * 32 + mb) * 64 + (lp + rr)) * 8 + jj;
          outH[a] = __float2half(acc[i][j][rr]);
        }
      }
    }
  }
#undef LOADCQ0
#undef LOADCQ1
#undef DEQD
#undef BODY
}

// x fp32 row-major [512][4096] -> packed f16 fragment layout.
__global__ void cast_pack_kernel(const float* __restrict__ x,
                                 __half* __restrict__ xp, int nGrp) {
  int pid = blockIdx.x * blockDim.x + threadIdx.x;   // one per 8 halfs
  if (pid >= nGrp) return;
  const int lane = pid & 63;
  const int grp  = pid >> 6;
  const int mb   = grp & 31;          // M=512 -> 32 m-tiles
  const int kb   = grp >> 5;
  const int m = mb * 16 + (lane & 15);
  const int k = kb * 32 + ((lane >> 4) << 3);
  const float4* src = (const float4*)(x + (size_t)m * 4096 + k);
  float4 v0 = src[0], v1 = src[1];
  __half2 h0 = __floats2half2_rn(v0.x, v0.y), h1 = __floats2half2_rn(v0.z, v0.w);
  __half2 h2 = __floats2half2_rn(v1.x, v1.y), h3 = __floats2half2_rn(v1.z, v1.w);
  uint4 o;
  o.x = *(const unsigned*)&h0; o.y = *(const unsigned*)&h1;
  o.z = *(const unsigned*)&h2; o.w = *(const unsigned*)&h3;
  ((uint4*)xp)[pid] = o;
}

// elementwise silu(g)*u — layout-agnostic (g,u share the packed layout).
__global__ void swiglu_kernel(const __half* __restrict__ g,
                              const __half* __restrict__ u,
                              __half* __restrict__ h, int n2) {
  int i = blockIdx.x * blockDim.x + threadIdx.x;
  if (i < n2) {
    float2 gf = __half22float2(((const __half2*)g)[i]);
    float2 uf = __half22float2(((const __half2*)u)[i]);
    float h0 = gf.x / (1.f + __expf(-gf.x)) * uf.x;
    float h1 = gf.y / (1.f + __expf(-gf.y)) * uf.y;
    ((__half2*)h)[i] = __floats2half2_rn(h0, h1);
  }
}

extern "C" void kernel_launch(void* const* d_in, const int* in_sizes, int n_in,
                              void* d_out, int out_size, void* d_ws, size_t ws_size,
                              hipStream_t stream)
{
  (void)in_sizes; (void)n_in; (void)ws_size;
  const float* x            = (const float*)d_in[0];
  const int*   gate_codes   = (const int*)d_in[1];
  const float* gate_absmax  = (const float*)d_in[2];
  const int*   up_codes     = (const int*)d_in[3];
  const float* up_absmax    = (const float*)d_in[4];
  const int*   down_codes   = (const int*)d_in[5];
  const float* down_absmax  = (const float*)d_in[6];
  float* out = (float*)d_out;

  // ws layout (bytes):
  //  xp 4.19MB | g 11.27MB | u 11.27MB |
  //  pg 22.5MB | pu 22.5MB | pd 22.5MB | amg 2.82MB | amu 2.82MB | amd 2.82MB
  __half* xp = (__half*)d_ws;
  __half* g  = xp + (size_t)512 * 4096;
  __half* u  = g  + (size_t)512 * 11008;
  unsigned char* pg = (unsigned char*)(u + (size_t)512 * 11008);
  unsigned char* pu = pg + (size_t)172 * 64 * 2048;   // 172 tiles x 64 kb x 2KB
  unsigned char* pd = pu + (size_t)172 * 64 * 2048;
  float* amg = (float*)(pd + (size_t)64 * 172 * 2048);
  float* amu = amg + (size_t)172 * 64 * 64;
  float* amd = amu + (size_t)172 * 64 * 64;

  hipMemsetAsync(d_out, 0, (size_t)out_size * sizeof(float), stream);

  cast_pack_kernel<<<1024, 256, 0, stream>>>(x, xp, (512 * 4096) / 8);

  // repack: gate/up (172 tiles x 16 kbgs = 2752), down (64 x 43 = 2752)
  repack_kernel<<<2752, 256, 0, stream>>>(gate_codes, gate_absmax, pg, amg,
                                          4096, 64, 16);
  repack_kernel<<<2752, 256, 0, stream>>>(up_codes, up_absmax, pu, amu,
                                          4096, 64, 16);
  repack_kernel<<<2752, 256, 0, stream>>>(down_codes, down_absmax, pd, amd,
                                          11008, 172, 43);

  // fused gate+up: 2 Mt x 172 Nt x 2 mats = 688 blocks
  gemm_nf4<false><<<688, 256, 0, stream>>>(xp, pg, amg, pu, amu,
                                           g, u, nullptr,
                                           11008, 4096, 4096, 172);

  swiglu_kernel<<<11008, 256, 0, stream>>>(g, u, g, (512 * 11008) / 2);

  // down: out += h * Wd^T, split-K=4: 2 Mt x 64 Nt x 4 = 512 blocks
  gemm_nf4<true><<<512, 256, 0, stream>>>(g, pd, amd,
                                          nullptr, nullptr, nullptr, nullptr,
                                          out, 4096, 11008, 2752, 64);
}